// Round 20
// baseline (234.386 us; speedup 1.0000x reference)
//
#include <hip/hip_runtime.h>

#define NUSERS 100000
#define NITEMS 50000
#define DIM 64
#define NNZ 1600000
#define ALPHA 0.1f
#define TROWS (NUSERS + NITEMS)   // 150000 combined rows
#define LSTRIDE (TROWS * DIM)
#define NEDGES (2 * NNZ)          // 3.2M combined edges

// Uniform pull buckets: 32 rows, 16 segments x 2 rows.
#define NBUCK_U (NUSERS / 32)               // 3125 (exact)
#define NBUCK_I ((NITEMS + 31) / 32)        // 1563
#define NBUCK (NBUCK_U + NBUCK_I)           // 4688 (pull grid)
// Coarse scatter bins: 256 rows both sides (8 buckets each)
#define NSCAT_U ((NUSERS + 255) / 256)      // 391
#define NSCAT_I ((NITEMS + 255) / 256)      // 196
#define NSCAT (NSCAT_U + NSCAT_I)           // 587
// segptr: 128 slots per coarse bin; users [0, 391*128), items from SEG_IBASE.
#define SEG_IBASE (NSCAT_U * 128)           // 50048
#define NSEG_PAD (SEG_IBASE + NSCAT_I * 128) // 75136

#define CH4 512                                 // int4 per block per array (hist)
#define NCHUNK_H ((NNZ / 4 + CH4 - 1) / CH4)    // 782
#define CH_S 4096                               // edges per scatter block
#define NCHUNK_S ((NEDGES + CH_S - 1) / CH_S)   // 782

typedef float vfloat4 __attribute__((ext_vector_type(4)));

__device__ __forceinline__ unsigned short f2bf(float f) {
    unsigned u = __float_as_uint(f);
    unsigned r = (u + 0x7FFFu + ((u >> 16) & 1u)) >> 16;   // RNE
    return (unsigned short)r;
}

__device__ __forceinline__ float bf_lo(unsigned u) { return __uint_as_float(u << 16); }
__device__ __forceinline__ float bf_hi(unsigned u) { return __uint_as_float(u & 0xFFFF0000u); }

// ---------------- layer-0 copy + bf16 table ----------------
__global__ __launch_bounds__(256) void init_copy_kernel(const float4* __restrict__ ue,
                                                        const float4* __restrict__ ie,
                                                        float4* __restrict__ out,
                                                        ushort4* __restrict__ xb0) {
    const int nU4 = NUSERS * DIM / 4;
    const int nT4 = TROWS * DIM / 4;
    int i = blockIdx.x * 256 + threadIdx.x;
    if (i >= nT4) return;
    float4 v = (i < nU4) ? ue[i] : ie[i - nU4];
    out[i] = v;
    ushort4 b;
    b.x = f2bf(v.x); b.y = f2bf(v.y); b.z = f2bf(v.z); b.w = f2bf(v.w);
    xb0[i] = b;
}

// ---------------- coarse-bin histogram (int4 loads, block-privatized) ----------------
__global__ __launch_bounds__(256) void bucket_hist_kernel(const int4* __restrict__ ui_rows4,
                                                          const int4* __restrict__ iu_rows4,
                                                          int* __restrict__ gcounts) {
    __shared__ int h[NSCAT];
    for (int t = threadIdx.x; t < NSCAT; t += 256) h[t] = 0;
    __syncthreads();
    int base = blockIdx.x * CH4;
    const int n4 = NNZ / 4;   // 400000, exact
    for (int j = threadIdx.x; j < CH4; j += 256) {
        int i = base + j;
        if (i >= n4) break;
        int4 ru = ui_rows4[i];
        atomicAdd(&h[ru.x >> 8], 1);
        atomicAdd(&h[ru.y >> 8], 1);
        atomicAdd(&h[ru.z >> 8], 1);
        atomicAdd(&h[ru.w >> 8], 1);
        int4 ri = iu_rows4[i];
        atomicAdd(&h[NSCAT_U + (ri.x >> 8)], 1);
        atomicAdd(&h[NSCAT_U + (ri.y >> 8)], 1);
        atomicAdd(&h[NSCAT_U + (ri.z >> 8)], 1);
        atomicAdd(&h[NSCAT_U + (ri.w >> 8)], 1);
    }
    __syncthreads();
    for (int t = threadIdx.x; t < NSCAT; t += 256) {
        int c = h[t];
        if (c) atomicAdd(&gcounts[t], c);
    }
}

// ---------------- exclusive scan of coarse-bin counts (one wave) ----------------
__global__ void scan_buckets_kernel(const int* __restrict__ gcounts,
                                    int* __restrict__ gbase,
                                    int* __restrict__ gcursor) {
    int lane = threadIdx.x;   // blockDim = 64, single wave
    int carry = 0;
    for (int b0 = 0; b0 < NSCAT; b0 += 64) {
        int idx = b0 + lane;
        int c = (idx < NSCAT) ? gcounts[idx] : 0;
        int x = c;
        for (int off = 1; off < 64; off <<= 1) {
            int u = __shfl_up(x, off, 64);
            if (lane >= off) x += u;
        }
        int excl = carry + x - c;
        if (idx < NSCAT) { gbase[idx] = excl; gcursor[idx] = excl; }
        carry += __shfl(x, 63, 64);
    }
}

// ---------------- coarse scatter: contiguous per-(block,bin) runs ----------------
// payload word0 = src | (rl << 18)  (src < 2^18; rl < 256 both sides)
__global__ __launch_bounds__(512) void bin_scatter_kernel(
    const int* __restrict__ ui_rows, const int* __restrict__ ui_cols,
    const float* __restrict__ ui_vals,
    const int* __restrict__ iu_rows, const int* __restrict__ iu_cols,
    const float* __restrict__ iu_vals,
    int* __restrict__ gcursor, int2* __restrict__ binned)
{
    __shared__ int h[NSCAT];
    __shared__ int bbase[NSCAT];
    for (int t = threadIdx.x; t < NSCAT; t += 512) h[t] = 0;
    __syncthreads();
    int base = blockIdx.x * CH_S;
    for (int j = threadIdx.x; j < CH_S; j += 512) {
        int i = base + j;
        if (i >= NEDGES) break;
        int bkt;
        if (i < NNZ) bkt = ui_rows[i] >> 8;
        else         bkt = NSCAT_U + (iu_rows[i - NNZ] >> 8);
        atomicAdd(&h[bkt], 1);
    }
    __syncthreads();
    for (int t = threadIdx.x; t < NSCAT; t += 512) {
        int c = h[t];
        bbase[t] = c ? atomicAdd(&gcursor[t], c) : 0;
        h[t] = 0;
    }
    __syncthreads();
    for (int j = threadIdx.x; j < CH_S; j += 512) {
        int i = base + j;
        if (i >= NEDGES) break;
        int bkt, rl, src; float val;
        if (i < NNZ) {
            int r = ui_rows[i];
            bkt = r >> 8; rl = r & 255;
            src = NUSERS + ui_cols[i]; val = ui_vals[i];
        } else {
            int k = i - NNZ;
            int r = iu_rows[k];
            bkt = NSCAT_U + (r >> 8); rl = r & 255;
            src = iu_cols[k]; val = iu_vals[k];
        }
        int off = atomicAdd(&h[bkt], 1);
        binned[bbase[bkt] + off] = make_int2(src | (rl << 18), __float_as_int(val));
    }
}

// ---------------- coarse-bin sort: 2048 keys = 128 2-row-segments x 16 tiles ----------------
// One block (1024 thr) per coarse bin. Uniform: slot bs = rl>>1, sub = rl&1.
// Within a segment, edges are src-tile-ordered (tile = src>>14, 2MB windows).
__global__ __launch_bounds__(1024) void csr_bin_sort_kernel(
    const int* __restrict__ gbase, const int* __restrict__ gcounts,
    const int2* __restrict__ binned, int2* __restrict__ binned2,
    int2* __restrict__ segptr)
{
    __shared__ int h[2048];
    __shared__ int off[2048];   // inclusive prefix
    __shared__ int cur[2048];
    __shared__ int s2[1024];
    int cb = blockIdx.x;
    bool isu = (cb < NSCAT_U);
    int s = gbase[cb];
    int n = gcounts[cb];
    int t = threadIdx.x;
    h[t] = 0; h[t + 1024] = 0;
    __syncthreads();
    for (int k = t; k < n; k += 1024) {
        unsigned w = (unsigned)binned[s + k].x;
        int rl = (int)(w >> 18);
        int src = (int)(w & 0x3FFFFu);
        atomicAdd(&h[(rl >> 1) * 16 + (src >> 14)], 1);
    }
    __syncthreads();
    // scan 2048 keys: 2 keys/thread + 1024-wide LDS doubling scan
    int e0 = h[2 * t], e1 = h[2 * t + 1];
    int ps = e0 + e1;
    s2[t] = ps;
    __syncthreads();
    for (int d = 1; d < 1024; d <<= 1) {
        int v = (t >= d) ? s2[t - d] : 0;
        __syncthreads();
        s2[t] += v;
        __syncthreads();
    }
    int exclp = s2[t] - ps;
    off[2 * t] = exclp + e0;
    off[2 * t + 1] = exclp + e0 + e1;
    cur[2 * t] = exclp;
    cur[2 * t + 1] = exclp + e0;
    __syncthreads();
    if (t < 128) {
        int start = s + ((t == 0) ? 0 : off[t * 16 - 1]);
        int end   = s + off[t * 16 + 15];
        int gseg = isu ? (cb * 128 + t)
                       : (SEG_IBASE + (cb - NSCAT_U) * 128 + t);
        segptr[gseg] = make_int2(start, end);
    }
    for (int k = t; k < n; k += 1024) {
        int2 m = binned[s + k];
        unsigned w = (unsigned)m.x;
        int rl = (int)(w >> 18);
        int src = (int)(w & 0x3FFFFu);
        int pos = atomicAdd(&cur[(rl >> 1) * 16 + (src >> 14)], 1);
        binned2[s + pos] = make_int2(src | ((rl & 1) << 18), m.y);
    }
}

// ---------------- segmented pull: uniform 2-row segments, reg-streamed cc ----------------
#define EDGE_ACC2(mx, my)                                                     \
    do {                                                                      \
        unsigned rr = ((unsigned)(mx) >> 18) & 1u;                            \
        float v = __int_as_float(my);                                         \
        uint2 xw = *(const uint2*)(xp + (size_t)((mx) & 0x3FFFF) * DIM);      \
        float xv0 = bf_lo(xw.x), xv1 = bf_hi(xw.x);                           \
        float xv2 = bf_lo(xw.y), xv3 = bf_hi(xw.y);                           \
        float p0 = rr ? 0.f : v;                                              \
        float p1 = rr ? v : 0.f;                                              \
        a0.x = fmaf(p0, xv0, a0.x); a0.y = fmaf(p0, xv1, a0.y);               \
        a0.z = fmaf(p0, xv2, a0.z); a0.w = fmaf(p0, xv3, a0.w);               \
        a1.x = fmaf(p1, xv0, a1.x); a1.y = fmaf(p1, xv1, a1.y);               \
        a1.z = fmaf(p1, xv2, a1.z); a1.w = fmaf(p1, xv3, a1.w);               \
    } while (0)

#define ROW_OUT(ar, r)                                                        \
    do {                                                                      \
        int row = row0 + (r);                                                 \
        if (row < TROWS) {                                                    \
            size_t obase = (size_t)row * DIM + l16 * 4;                       \
            uint2 eb = *(const uint2*)(xb0 + obase);                          \
            vfloat4 o;                                                        \
            o.x = fmaf(ALPHA, bf_lo(eb.x), (ar).x);                           \
            o.y = fmaf(ALPHA, bf_hi(eb.x), (ar).y);                           \
            o.z = fmaf(ALPHA, bf_lo(eb.y), (ar).z);                           \
            o.w = fmaf(ALPHA, bf_hi(eb.y), (ar).w);                           \
            __builtin_nontemporal_store(o, (vfloat4*)(outL + obase));         \
            if (WRITE_BF16) {                                                 \
                ushort4 bb;                                                   \
                bb.x = f2bf(o.x); bb.y = f2bf(o.y);                           \
                bb.z = f2bf(o.z); bb.w = f2bf(o.w);                           \
                *(ushort4*)(xb_next + obase) = bb;                            \
            }                                                                 \
        }                                                                     \
    } while (0)

template <int WRITE_BF16>
__global__ __launch_bounds__(256) void pull_seg_kernel(
    const int2* __restrict__ segptr,
    const int2* __restrict__ cc,
    const unsigned short* __restrict__ xb_prev,  // bf16 gather table (prev layer)
    const unsigned short* __restrict__ xb0,      // bf16 layer-0 table (alpha residual)
    float* __restrict__ outL,                    // f32 combined output layer
    unsigned short* __restrict__ xb_next)        // bf16 table for next layer
{
    int b = blockIdx.x;
    int wid = threadIdx.x >> 6;
    int lane = threadIdx.x & 63;
    int grp = lane >> 4;
    int l16 = lane & 15;
    int gb = lane & 48;       // group base lane
    int seg = wid * 4 + grp;

    const unsigned short* xp = xb_prev + l16 * 4;

    int segidx = (b < NBUCK_U) ? (b * 16 + seg)
                               : (SEG_IBASE + (b - NBUCK_U) * 16 + seg);
    int2 sp = segptr[segidx];
    int e = sp.x, end = sp.y;
    float4 a0 = make_float4(0.f, 0.f, 0.f, 0.f);
    float4 a1 = a0;

    while (e + 8 <= end) {
        int2 my = cc[e + (l16 & 7)];   // 8 edges of this group in registers
#pragma unroll
        for (int j = 0; j < 8; ++j) {
            int mx = __shfl(my.x, gb + j, 64);
            int mv = __shfl(my.y, gb + j, 64);
            EDGE_ACC2(mx, mv);
        }
        e += 8;
    }
    for (; e < end; ++e) {
        int2 m0 = cc[e];
        EDGE_ACC2(m0.x, m0.y);
    }

    int row0 = b * 32 + seg * 2;   // holds for users AND items (3125*32 == NUSERS)
    ROW_OUT(a0, 0);
    ROW_OUT(a1, 1);
}

// ---------------- fallback (round-1 atomic path) ----------------
__global__ __launch_bounds__(256) void init_out_kernel(const float4* __restrict__ ue,
                                                       const float4* __restrict__ ie,
                                                       float4* __restrict__ out) {
    const int nU4 = NUSERS * DIM / 4;
    const int nT4 = TROWS * DIM / 4;
    int i = blockIdx.x * 256 + threadIdx.x;
    if (i >= nT4) return;
    float4 v = (i < nU4) ? ue[i] : ie[i - nU4];
    out[i] = v;
    float4 a = make_float4(ALPHA * v.x, ALPHA * v.y, ALPHA * v.z, ALPHA * v.w);
    out[nT4 + i] = a;
    out[2 * nT4 + i] = a;
}

__global__ __launch_bounds__(256) void spmm_layer_kernel(
    const int* __restrict__ ui_rows, const int* __restrict__ ui_cols,
    const float* __restrict__ ui_vals,
    const int* __restrict__ iu_rows, const int* __restrict__ iu_cols,
    const float* __restrict__ iu_vals,
    const float* __restrict__ x_items, const float* __restrict__ x_users,
    float* __restrict__ y_users, float* __restrict__ y_items)
{
    unsigned tid = blockIdx.x * 256u + threadIdx.x;
    unsigned d = tid & 63u;
    unsigned e = tid >> 6;
    if (e < NNZ) {
        int r = ui_rows[e];
        int c = ui_cols[e];
        float v = ui_vals[e];
        atomicAdd(&y_users[r * DIM + d], v * x_items[c * DIM + d]);
    } else {
        e -= NNZ;
        if (e < NNZ) {
            int r = iu_rows[e];
            int c = iu_cols[e];
            float v = iu_vals[e];
            atomicAdd(&y_items[r * DIM + d], v * x_users[c * DIM + d]);
        }
    }
}

extern "C" void kernel_launch(void* const* d_in, const int* in_sizes, int n_in,
                              void* d_out, int out_size, void* d_ws, size_t ws_size,
                              hipStream_t stream) {
    const float* ue      = (const float*)d_in[0];
    const float* ie      = (const float*)d_in[1];
    const float* ui_vals = (const float*)d_in[2];
    const float* iu_vals = (const float*)d_in[3];
    const int*   ui_rows = (const int*)d_in[4];
    const int*   ui_cols = (const int*)d_in[5];
    const int*   iu_rows = (const int*)d_in[6];
    const int*   iu_cols = (const int*)d_in[7];
    float* out = (float*)d_out;

    float* L1 = out + (size_t)LSTRIDE;
    float* L2 = out + (size_t)2 * LSTRIDE;

    // ws layout: gcounts[1024] gbase[1024] gcursor[1024] | segptr int2[NSEG_PAD]
    //            | binned int2[NEDGES] | binned2 int2[NEDGES]
    //            | xb0 ushort[TROWS*64] | xb1 ushort[TROWS*64]
    const size_t NB_PAD = 1024;
    const size_t cnt_bytes    = NB_PAD * 3 * 4;              // 12288
    const size_t seg_bytes    = (size_t)NSEG_PAD * 8;        // 601088
    const size_t hdr_bytes    = cnt_bytes + seg_bytes;       // 613376, 8B-aligned
    const size_t binned_bytes = (size_t)NEDGES * 8;          // 25.6 MB
    const size_t xb_bytes     = (size_t)TROWS * DIM * 2;     // 19.2 MB
    const size_t need_bf16 = hdr_bytes + 2 * binned_bytes + 2 * xb_bytes;  // ~90.6 MB

    if (ws_size < need_bf16) {
        // fallback: atomic scatter path (round-1, known-good)
        const int nT4 = TROWS * DIM / 4;
        init_out_kernel<<<(nT4 + 255) / 256, 256, 0, stream>>>(
            (const float4*)ue, (const float4*)ie, (float4*)out);
        float* u1 = L1; float* i1 = L1 + (size_t)NUSERS * DIM;
        float* u2 = L2; float* i2 = L2 + (size_t)NUSERS * DIM;
        const unsigned nblocks = (2u * NNZ * 64u) / 256u;
        spmm_layer_kernel<<<nblocks, 256, 0, stream>>>(
            ui_rows, ui_cols, ui_vals, iu_rows, iu_cols, iu_vals, ie, ue, u1, i1);
        spmm_layer_kernel<<<nblocks, 256, 0, stream>>>(
            ui_rows, ui_cols, ui_vals, iu_rows, iu_cols, iu_vals, i1, u1, u2, i2);
        return;
    }

    int* gcounts = (int*)d_ws;
    int* gbase   = gcounts + NB_PAD;
    int* gcursor = gbase + NB_PAD;
    int2* segptr  = (int2*)((char*)d_ws + cnt_bytes);
    int2* binned  = (int2*)((char*)d_ws + hdr_bytes);
    int2* binned2 = (int2*)((char*)binned + binned_bytes);
    unsigned short* xb0 = (unsigned short*)((char*)binned2 + binned_bytes);
    unsigned short* xb1 = xb0 + (size_t)TROWS * DIM;

    hipMemsetAsync(gcounts, 0, NB_PAD * sizeof(int), stream);

    const int nT4 = TROWS * DIM / 4;
    init_copy_kernel<<<(nT4 + 255) / 256, 256, 0, stream>>>(
        (const float4*)ue, (const float4*)ie, (float4*)out, (ushort4*)xb0);

    bucket_hist_kernel<<<NCHUNK_H, 256, 0, stream>>>(
        (const int4*)ui_rows, (const int4*)iu_rows, gcounts);
    scan_buckets_kernel<<<1, 64, 0, stream>>>(gcounts, gbase, gcursor);
    bin_scatter_kernel<<<NCHUNK_S, 512, 0, stream>>>(
        ui_rows, ui_cols, ui_vals, iu_rows, iu_cols, iu_vals, gcursor, binned);
    csr_bin_sort_kernel<<<NSCAT, 1024, 0, stream>>>(
        gbase, gcounts, binned, binned2, segptr);

    pull_seg_kernel<1><<<NBUCK, 256, 0, stream>>>(
        segptr, binned2, xb0, xb0, L1, xb1);
    pull_seg_kernel<0><<<NBUCK, 256, 0, stream>>>(
        segptr, binned2, xb1, xb0, L2, nullptr);
}

// Round 21
// 222.422 us; speedup vs baseline: 1.0538x; 1.0538x over previous
//
#include <hip/hip_runtime.h>

#define NUSERS 100000
#define NITEMS 50000
#define DIM 64
#define NNZ 1600000
#define ALPHA 0.1f
#define TROWS (NUSERS + NITEMS)   // 150000 combined rows
#define LSTRIDE (TROWS * DIM)
#define NEDGES (2 * NNZ)          // 3.2M combined edges

// Uniform pull buckets: 32 rows, 16 segments x 2 rows.
#define NBUCK_U (NUSERS / 32)               // 3125 (exact)
#define NBUCK_I ((NITEMS + 31) / 32)        // 1563
#define NBUCK (NBUCK_U + NBUCK_I)           // 4688 (pull grid)
// Coarse scatter bins: 256 rows both sides (8 buckets each)
#define NSCAT_U ((NUSERS + 255) / 256)      // 391
#define NSCAT_I ((NITEMS + 255) / 256)      // 196
#define NSCAT (NSCAT_U + NSCAT_I)           // 587
// segptr: 128 slots per coarse bin; users [0, 391*128), items from SEG_IBASE.
#define SEG_IBASE (NSCAT_U * 128)           // 50048
#define NSEG_PAD (SEG_IBASE + NSCAT_I * 128) // 75136

#define CH4 512                                 // int4 per block per array (hist)
#define NCHUNK_H ((NNZ / 4 + CH4 - 1) / CH4)    // 782
#define CH_S 8192                               // edges per scatter block
#define NCHUNK_S ((NEDGES + CH_S - 1) / CH_S)   // 391 (long runs, low write amp)

typedef float vfloat4 __attribute__((ext_vector_type(4)));

__device__ __forceinline__ unsigned short f2bf(float f) {
    unsigned u = __float_as_uint(f);
    unsigned r = (u + 0x7FFFu + ((u >> 16) & 1u)) >> 16;   // RNE
    return (unsigned short)r;
}

__device__ __forceinline__ float bf_lo(unsigned u) { return __uint_as_float(u << 16); }
__device__ __forceinline__ float bf_hi(unsigned u) { return __uint_as_float(u & 0xFFFF0000u); }

// ---------------- layer-0 copy + bf16 table ----------------
__global__ __launch_bounds__(256) void init_copy_kernel(const float4* __restrict__ ue,
                                                        const float4* __restrict__ ie,
                                                        float4* __restrict__ out,
                                                        ushort4* __restrict__ xb0) {
    const int nU4 = NUSERS * DIM / 4;
    const int nT4 = TROWS * DIM / 4;
    int i = blockIdx.x * 256 + threadIdx.x;
    if (i >= nT4) return;
    float4 v = (i < nU4) ? ue[i] : ie[i - nU4];
    out[i] = v;
    ushort4 b;
    b.x = f2bf(v.x); b.y = f2bf(v.y); b.z = f2bf(v.z); b.w = f2bf(v.w);
    xb0[i] = b;
}

// ---------------- coarse-bin histogram (int4 loads, block-privatized) ----------------
__global__ __launch_bounds__(256) void bucket_hist_kernel(const int4* __restrict__ ui_rows4,
                                                          const int4* __restrict__ iu_rows4,
                                                          int* __restrict__ gcounts) {
    __shared__ int h[NSCAT];
    for (int t = threadIdx.x; t < NSCAT; t += 256) h[t] = 0;
    __syncthreads();
    int base = blockIdx.x * CH4;
    const int n4 = NNZ / 4;   // 400000, exact
    for (int j = threadIdx.x; j < CH4; j += 256) {
        int i = base + j;
        if (i >= n4) break;
        int4 ru = ui_rows4[i];
        atomicAdd(&h[ru.x >> 8], 1);
        atomicAdd(&h[ru.y >> 8], 1);
        atomicAdd(&h[ru.z >> 8], 1);
        atomicAdd(&h[ru.w >> 8], 1);
        int4 ri = iu_rows4[i];
        atomicAdd(&h[NSCAT_U + (ri.x >> 8)], 1);
        atomicAdd(&h[NSCAT_U + (ri.y >> 8)], 1);
        atomicAdd(&h[NSCAT_U + (ri.z >> 8)], 1);
        atomicAdd(&h[NSCAT_U + (ri.w >> 8)], 1);
    }
    __syncthreads();
    for (int t = threadIdx.x; t < NSCAT; t += 256) {
        int c = h[t];
        if (c) atomicAdd(&gcounts[t], c);
    }
}

// ---------------- exclusive scan of coarse-bin counts (one wave) ----------------
__global__ void scan_buckets_kernel(const int* __restrict__ gcounts,
                                    int* __restrict__ gbase,
                                    int* __restrict__ gcursor) {
    int lane = threadIdx.x;   // blockDim = 64, single wave
    int carry = 0;
    for (int b0 = 0; b0 < NSCAT; b0 += 64) {
        int idx = b0 + lane;
        int c = (idx < NSCAT) ? gcounts[idx] : 0;
        int x = c;
        for (int off = 1; off < 64; off <<= 1) {
            int u = __shfl_up(x, off, 64);
            if (lane >= off) x += u;
        }
        int excl = carry + x - c;
        if (idx < NSCAT) { gbase[idx] = excl; gcursor[idx] = excl; }
        carry += __shfl(x, 63, 64);
    }
}

// ---------------- coarse scatter: contiguous per-(block,bin) runs ----------------
// payload word0 = src | (rl << 18)  (src < 2^18; rl < 256 both sides)
// 1024 threads (16 waves) with grid 391: TLP doubled vs round 19 WITHOUT
// shrinking runs (write amp depends on grid x bins, not threads).
__global__ __launch_bounds__(1024) void bin_scatter_kernel(
    const int* __restrict__ ui_rows, const int* __restrict__ ui_cols,
    const float* __restrict__ ui_vals,
    const int* __restrict__ iu_rows, const int* __restrict__ iu_cols,
    const float* __restrict__ iu_vals,
    int* __restrict__ gcursor, int2* __restrict__ binned)
{
    __shared__ int h[NSCAT];
    __shared__ int bbase[NSCAT];
    for (int t = threadIdx.x; t < NSCAT; t += 1024) h[t] = 0;
    __syncthreads();
    int base = blockIdx.x * CH_S;
    for (int j = threadIdx.x; j < CH_S; j += 1024) {
        int i = base + j;
        if (i >= NEDGES) break;
        int bkt;
        if (i < NNZ) bkt = ui_rows[i] >> 8;
        else         bkt = NSCAT_U + (iu_rows[i - NNZ] >> 8);
        atomicAdd(&h[bkt], 1);
    }
    __syncthreads();
    for (int t = threadIdx.x; t < NSCAT; t += 1024) {
        int c = h[t];
        bbase[t] = c ? atomicAdd(&gcursor[t], c) : 0;
        h[t] = 0;
    }
    __syncthreads();
    for (int j = threadIdx.x; j < CH_S; j += 1024) {
        int i = base + j;
        if (i >= NEDGES) break;
        int bkt, rl, src; float val;
        if (i < NNZ) {
            int r = ui_rows[i];
            bkt = r >> 8; rl = r & 255;
            src = NUSERS + ui_cols[i]; val = ui_vals[i];
        } else {
            int k = i - NNZ;
            int r = iu_rows[k];
            bkt = NSCAT_U + (r >> 8); rl = r & 255;
            src = iu_cols[k]; val = iu_vals[k];
        }
        int off = atomicAdd(&h[bkt], 1);
        binned[bbase[bkt] + off] = make_int2(src | (rl << 18), __float_as_int(val));
    }
}

// ---------------- coarse-bin sort: 2048 keys = 128 2-row-segments x 16 tiles ----------------
// One block (1024 thr) per coarse bin. Uniform: slot bs = rl>>1, sub = rl&1.
// Within a segment, edges are src-tile-ordered (tile = src>>14, 2MB windows).
__global__ __launch_bounds__(1024) void csr_bin_sort_kernel(
    const int* __restrict__ gbase, const int* __restrict__ gcounts,
    const int2* __restrict__ binned, int2* __restrict__ binned2,
    int2* __restrict__ segptr)
{
    __shared__ int h[2048];
    __shared__ int off[2048];   // inclusive prefix
    __shared__ int cur[2048];
    __shared__ int s2[1024];
    int cb = blockIdx.x;
    bool isu = (cb < NSCAT_U);
    int s = gbase[cb];
    int n = gcounts[cb];
    int t = threadIdx.x;
    h[t] = 0; h[t + 1024] = 0;
    __syncthreads();
    for (int k = t; k < n; k += 1024) {
        unsigned w = (unsigned)binned[s + k].x;
        int rl = (int)(w >> 18);
        int src = (int)(w & 0x3FFFFu);
        atomicAdd(&h[(rl >> 1) * 16 + (src >> 14)], 1);
    }
    __syncthreads();
    // scan 2048 keys: 2 keys/thread + 1024-wide LDS doubling scan
    int e0 = h[2 * t], e1 = h[2 * t + 1];
    int ps = e0 + e1;
    s2[t] = ps;
    __syncthreads();
    for (int d = 1; d < 1024; d <<= 1) {
        int v = (t >= d) ? s2[t - d] : 0;
        __syncthreads();
        s2[t] += v;
        __syncthreads();
    }
    int exclp = s2[t] - ps;
    off[2 * t] = exclp + e0;
    off[2 * t + 1] = exclp + e0 + e1;
    cur[2 * t] = exclp;
    cur[2 * t + 1] = exclp + e0;
    __syncthreads();
    if (t < 128) {
        int start = s + ((t == 0) ? 0 : off[t * 16 - 1]);
        int end   = s + off[t * 16 + 15];
        int gseg = isu ? (cb * 128 + t)
                       : (SEG_IBASE + (cb - NSCAT_U) * 128 + t);
        segptr[gseg] = make_int2(start, end);
    }
    for (int k = t; k < n; k += 1024) {
        int2 m = binned[s + k];
        unsigned w = (unsigned)m.x;
        int rl = (int)(w >> 18);
        int src = (int)(w & 0x3FFFFu);
        int pos = atomicAdd(&cur[(rl >> 1) * 16 + (src >> 14)], 1);
        binned2[s + pos] = make_int2(src | ((rl & 1) << 18), m.y);
    }
}

// ---------------- segmented pull: uniform 2-row segments, reg-streamed cc ----------------
#define EDGE_ACC2(mx, my)                                                     \
    do {                                                                      \
        unsigned rr = ((unsigned)(mx) >> 18) & 1u;                            \
        float v = __int_as_float(my);                                         \
        uint2 xw = *(const uint2*)(xp + (size_t)((mx) & 0x3FFFF) * DIM);      \
        float xv0 = bf_lo(xw.x), xv1 = bf_hi(xw.x);                           \
        float xv2 = bf_lo(xw.y), xv3 = bf_hi(xw.y);                           \
        float p0 = rr ? 0.f : v;                                              \
        float p1 = rr ? v : 0.f;                                              \
        a0.x = fmaf(p0, xv0, a0.x); a0.y = fmaf(p0, xv1, a0.y);               \
        a0.z = fmaf(p0, xv2, a0.z); a0.w = fmaf(p0, xv3, a0.w);               \
        a1.x = fmaf(p1, xv0, a1.x); a1.y = fmaf(p1, xv1, a1.y);               \
        a1.z = fmaf(p1, xv2, a1.z); a1.w = fmaf(p1, xv3, a1.w);               \
    } while (0)

#define ROW_OUT(ar, r)                                                        \
    do {                                                                      \
        int row = row0 + (r);                                                 \
        if (row < TROWS) {                                                    \
            size_t obase = (size_t)row * DIM + l16 * 4;                       \
            uint2 eb = *(const uint2*)(xb0 + obase);                          \
            vfloat4 o;                                                        \
            o.x = fmaf(ALPHA, bf_lo(eb.x), (ar).x);                           \
            o.y = fmaf(ALPHA, bf_hi(eb.x), (ar).y);                           \
            o.z = fmaf(ALPHA, bf_lo(eb.y), (ar).z);                           \
            o.w = fmaf(ALPHA, bf_hi(eb.y), (ar).w);                           \
            __builtin_nontemporal_store(o, (vfloat4*)(outL + obase));         \
            if (WRITE_BF16) {                                                 \
                ushort4 bb;                                                   \
                bb.x = f2bf(o.x); bb.y = f2bf(o.y);                           \
                bb.z = f2bf(o.z); bb.w = f2bf(o.w);                           \
                *(ushort4*)(xb_next + obase) = bb;                            \
            }                                                                 \
        }                                                                     \
    } while (0)

template <int WRITE_BF16>
__global__ __launch_bounds__(256) void pull_seg_kernel(
    const int2* __restrict__ segptr,
    const int2* __restrict__ cc,
    const unsigned short* __restrict__ xb_prev,  // bf16 gather table (prev layer)
    const unsigned short* __restrict__ xb0,      // bf16 layer-0 table (alpha residual)
    float* __restrict__ outL,                    // f32 combined output layer
    unsigned short* __restrict__ xb_next)        // bf16 table for next layer
{
    int b = blockIdx.x;
    int wid = threadIdx.x >> 6;
    int lane = threadIdx.x & 63;
    int grp = lane >> 4;
    int l16 = lane & 15;
    int gb = lane & 48;       // group base lane
    int seg = wid * 4 + grp;

    const unsigned short* xp = xb_prev + l16 * 4;

    int segidx = (b < NBUCK_U) ? (b * 16 + seg)
                               : (SEG_IBASE + (b - NBUCK_U) * 16 + seg);
    int2 sp = segptr[segidx];
    int e = sp.x, end = sp.y;
    float4 a0 = make_float4(0.f, 0.f, 0.f, 0.f);
    float4 a1 = a0;

    while (e + 8 <= end) {
        int2 my = cc[e + (l16 & 7)];   // 8 edges of this group in registers
#pragma unroll
        for (int j = 0; j < 8; ++j) {
            int mx = __shfl(my.x, gb + j, 64);
            int mv = __shfl(my.y, gb + j, 64);
            EDGE_ACC2(mx, mv);
        }
        e += 8;
    }
    for (; e < end; ++e) {
        int2 m0 = cc[e];
        EDGE_ACC2(m0.x, m0.y);
    }

    int row0 = b * 32 + seg * 2;   // holds for users AND items (3125*32 == NUSERS)
    ROW_OUT(a0, 0);
    ROW_OUT(a1, 1);
}

// ---------------- fallback (round-1 atomic path) ----------------
__global__ __launch_bounds__(256) void init_out_kernel(const float4* __restrict__ ue,
                                                       const float4* __restrict__ ie,
                                                       float4* __restrict__ out) {
    const int nU4 = NUSERS * DIM / 4;
    const int nT4 = TROWS * DIM / 4;
    int i = blockIdx.x * 256 + threadIdx.x;
    if (i >= nT4) return;
    float4 v = (i < nU4) ? ue[i] : ie[i - nU4];
    out[i] = v;
    float4 a = make_float4(ALPHA * v.x, ALPHA * v.y, ALPHA * v.z, ALPHA * v.w);
    out[nT4 + i] = a;
    out[2 * nT4 + i] = a;
}

__global__ __launch_bounds__(256) void spmm_layer_kernel(
    const int* __restrict__ ui_rows, const int* __restrict__ ui_cols,
    const float* __restrict__ ui_vals,
    const int* __restrict__ iu_rows, const int* __restrict__ iu_cols,
    const float* __restrict__ iu_vals,
    const float* __restrict__ x_items, const float* __restrict__ x_users,
    float* __restrict__ y_users, float* __restrict__ y_items)
{
    unsigned tid = blockIdx.x * 256u + threadIdx.x;
    unsigned d = tid & 63u;
    unsigned e = tid >> 6;
    if (e < NNZ) {
        int r = ui_rows[e];
        int c = ui_cols[e];
        float v = ui_vals[e];
        atomicAdd(&y_users[r * DIM + d], v * x_items[c * DIM + d]);
    } else {
        e -= NNZ;
        if (e < NNZ) {
            int r = iu_rows[e];
            int c = iu_cols[e];
            float v = iu_vals[e];
            atomicAdd(&y_items[r * DIM + d], v * x_users[c * DIM + d]);
        }
    }
}

extern "C" void kernel_launch(void* const* d_in, const int* in_sizes, int n_in,
                              void* d_out, int out_size, void* d_ws, size_t ws_size,
                              hipStream_t stream) {
    const float* ue      = (const float*)d_in[0];
    const float* ie      = (const float*)d_in[1];
    const float* ui_vals = (const float*)d_in[2];
    const float* iu_vals = (const float*)d_in[3];
    const int*   ui_rows = (const int*)d_in[4];
    const int*   ui_cols = (const int*)d_in[5];
    const int*   iu_rows = (const int*)d_in[6];
    const int*   iu_cols = (const int*)d_in[7];
    float* out = (float*)d_out;

    float* L1 = out + (size_t)LSTRIDE;
    float* L2 = out + (size_t)2 * LSTRIDE;

    // ws layout: gcounts[1024] gbase[1024] gcursor[1024] | segptr int2[NSEG_PAD]
    //            | binned int2[NEDGES] | binned2 int2[NEDGES]
    //            | xb0 ushort[TROWS*64] | xb1 ushort[TROWS*64]
    const size_t NB_PAD = 1024;
    const size_t cnt_bytes    = NB_PAD * 3 * 4;              // 12288
    const size_t seg_bytes    = (size_t)NSEG_PAD * 8;        // 601088
    const size_t hdr_bytes    = cnt_bytes + seg_bytes;       // 613376, 8B-aligned
    const size_t binned_bytes = (size_t)NEDGES * 8;          // 25.6 MB
    const size_t xb_bytes     = (size_t)TROWS * DIM * 2;     // 19.2 MB
    const size_t need_bf16 = hdr_bytes + 2 * binned_bytes + 2 * xb_bytes;  // ~90.6 MB

    if (ws_size < need_bf16) {
        // fallback: atomic scatter path (round-1, known-good)
        const int nT4 = TROWS * DIM / 4;
        init_out_kernel<<<(nT4 + 255) / 256, 256, 0, stream>>>(
            (const float4*)ue, (const float4*)ie, (float4*)out);
        float* u1 = L1; float* i1 = L1 + (size_t)NUSERS * DIM;
        float* u2 = L2; float* i2 = L2 + (size_t)NUSERS * DIM;
        const unsigned nblocks = (2u * NNZ * 64u) / 256u;
        spmm_layer_kernel<<<nblocks, 256, 0, stream>>>(
            ui_rows, ui_cols, ui_vals, iu_rows, iu_cols, iu_vals, ie, ue, u1, i1);
        spmm_layer_kernel<<<nblocks, 256, 0, stream>>>(
            ui_rows, ui_cols, ui_vals, iu_rows, iu_cols, iu_vals, i1, u1, u2, i2);
        return;
    }

    int* gcounts = (int*)d_ws;
    int* gbase   = gcounts + NB_PAD;
    int* gcursor = gbase + NB_PAD;
    int2* segptr  = (int2*)((char*)d_ws + cnt_bytes);
    int2* binned  = (int2*)((char*)d_ws + hdr_bytes);
    int2* binned2 = (int2*)((char*)binned + binned_bytes);
    unsigned short* xb0 = (unsigned short*)((char*)binned2 + binned_bytes);
    unsigned short* xb1 = xb0 + (size_t)TROWS * DIM;

    hipMemsetAsync(gcounts, 0, NB_PAD * sizeof(int), stream);

    const int nT4 = TROWS * DIM / 4;
    init_copy_kernel<<<(nT4 + 255) / 256, 256, 0, stream>>>(
        (const float4*)ue, (const float4*)ie, (float4*)out, (ushort4*)xb0);

    bucket_hist_kernel<<<NCHUNK_H, 256, 0, stream>>>(
        (const int4*)ui_rows, (const int4*)iu_rows, gcounts);
    scan_buckets_kernel<<<1, 64, 0, stream>>>(gcounts, gbase, gcursor);
    bin_scatter_kernel<<<NCHUNK_S, 1024, 0, stream>>>(
        ui_rows, ui_cols, ui_vals, iu_rows, iu_cols, iu_vals, gcursor, binned);
    csr_bin_sort_kernel<<<NSCAT, 1024, 0, stream>>>(
        gbase, gcounts, binned, binned2, segptr);

    pull_seg_kernel<1><<<NBUCK, 256, 0, stream>>>(
        segptr, binned2, xb0, xb0, L1, xb1);
    pull_seg_kernel<0><<<NBUCK, 256, 0, stream>>>(
        segptr, binned2, xb1, xb0, L2, nullptr);
}

// Round 22
// 221.725 us; speedup vs baseline: 1.0571x; 1.0031x over previous
//
#include <hip/hip_runtime.h>

#define NUSERS 100000
#define NITEMS 50000
#define DIM 64
#define NNZ 1600000
#define ALPHA 0.1f
#define TROWS (NUSERS + NITEMS)   // 150000 combined rows
#define LSTRIDE (TROWS * DIM)
#define NEDGES (2 * NNZ)          // 3.2M combined edges

// Uniform pull buckets: 32 rows, 16 segments x 2 rows.
#define NBUCK_U (NUSERS / 32)               // 3125 (exact)
#define NBUCK_I ((NITEMS + 31) / 32)        // 1563
#define NBUCK (NBUCK_U + NBUCK_I)           // 4688 (pull grid)
// Coarse scatter bins: 256 rows both sides (8 buckets each)
#define NSCAT_U ((NUSERS + 255) / 256)      // 391
#define NSCAT_I ((NITEMS + 255) / 256)      // 196
#define NSCAT (NSCAT_U + NSCAT_I)           // 587
// segptr: 128 slots per coarse bin; users [0, 391*128), items from SEG_IBASE.
#define SEG_IBASE (NSCAT_U * 128)           // 50048
#define NSEG_PAD (SEG_IBASE + NSCAT_I * 128) // 75136

#define CH4 512                                 // int4 per block per array (hist)
#define NCHUNK_H ((NNZ / 4 + CH4 - 1) / CH4)    // 782
#define CH_S 8192                               // edges per scatter block
#define NCHUNK_S ((NEDGES + CH_S - 1) / CH_S)   // 391 (long runs, low write amp)

typedef float vfloat4 __attribute__((ext_vector_type(4)));

__device__ __forceinline__ unsigned short f2bf(float f) {
    unsigned u = __float_as_uint(f);
    unsigned r = (u + 0x7FFFu + ((u >> 16) & 1u)) >> 16;   // RNE
    return (unsigned short)r;
}

__device__ __forceinline__ float bf_lo(unsigned u) { return __uint_as_float(u << 16); }
__device__ __forceinline__ float bf_hi(unsigned u) { return __uint_as_float(u & 0xFFFF0000u); }

// ---------------- layer-0 copy + bf16 table ----------------
__global__ __launch_bounds__(256) void init_copy_kernel(const float4* __restrict__ ue,
                                                        const float4* __restrict__ ie,
                                                        float4* __restrict__ out,
                                                        ushort4* __restrict__ xb0) {
    const int nU4 = NUSERS * DIM / 4;
    const int nT4 = TROWS * DIM / 4;
    int i = blockIdx.x * 256 + threadIdx.x;
    if (i >= nT4) return;
    float4 v = (i < nU4) ? ue[i] : ie[i - nU4];
    out[i] = v;
    ushort4 b;
    b.x = f2bf(v.x); b.y = f2bf(v.y); b.z = f2bf(v.z); b.w = f2bf(v.w);
    xb0[i] = b;
}

// ---------------- coarse-bin histogram (int4 loads, block-privatized) ----------------
__global__ __launch_bounds__(256) void bucket_hist_kernel(const int4* __restrict__ ui_rows4,
                                                          const int4* __restrict__ iu_rows4,
                                                          int* __restrict__ gcounts) {
    __shared__ int h[NSCAT];
    for (int t = threadIdx.x; t < NSCAT; t += 256) h[t] = 0;
    __syncthreads();
    int base = blockIdx.x * CH4;
    const int n4 = NNZ / 4;   // 400000, exact
    for (int j = threadIdx.x; j < CH4; j += 256) {
        int i = base + j;
        if (i >= n4) break;
        int4 ru = ui_rows4[i];
        atomicAdd(&h[ru.x >> 8], 1);
        atomicAdd(&h[ru.y >> 8], 1);
        atomicAdd(&h[ru.z >> 8], 1);
        atomicAdd(&h[ru.w >> 8], 1);
        int4 ri = iu_rows4[i];
        atomicAdd(&h[NSCAT_U + (ri.x >> 8)], 1);
        atomicAdd(&h[NSCAT_U + (ri.y >> 8)], 1);
        atomicAdd(&h[NSCAT_U + (ri.z >> 8)], 1);
        atomicAdd(&h[NSCAT_U + (ri.w >> 8)], 1);
    }
    __syncthreads();
    for (int t = threadIdx.x; t < NSCAT; t += 256) {
        int c = h[t];
        if (c) atomicAdd(&gcounts[t], c);
    }
}

// ---------------- exclusive scan of coarse-bin counts (one wave) ----------------
__global__ void scan_buckets_kernel(const int* __restrict__ gcounts,
                                    int* __restrict__ gbase,
                                    int* __restrict__ gcursor) {
    int lane = threadIdx.x;   // blockDim = 64, single wave
    int carry = 0;
    for (int b0 = 0; b0 < NSCAT; b0 += 64) {
        int idx = b0 + lane;
        int c = (idx < NSCAT) ? gcounts[idx] : 0;
        int x = c;
        for (int off = 1; off < 64; off <<= 1) {
            int u = __shfl_up(x, off, 64);
            if (lane >= off) x += u;
        }
        int excl = carry + x - c;
        if (idx < NSCAT) { gbase[idx] = excl; gcursor[idx] = excl; }
        carry += __shfl(x, 63, 64);
    }
}

// ---------------- coarse scatter: contiguous per-(block,bin) runs ----------------
// payload word0 = src | (rl << 18)  (src < 2^18; rl < 256 both sides)
__global__ __launch_bounds__(1024) void bin_scatter_kernel(
    const int* __restrict__ ui_rows, const int* __restrict__ ui_cols,
    const float* __restrict__ ui_vals,
    const int* __restrict__ iu_rows, const int* __restrict__ iu_cols,
    const float* __restrict__ iu_vals,
    int* __restrict__ gcursor, int2* __restrict__ binned)
{
    __shared__ int h[NSCAT];
    __shared__ int bbase[NSCAT];
    for (int t = threadIdx.x; t < NSCAT; t += 1024) h[t] = 0;
    __syncthreads();
    int base = blockIdx.x * CH_S;
    for (int j = threadIdx.x; j < CH_S; j += 1024) {
        int i = base + j;
        if (i >= NEDGES) break;
        int bkt;
        if (i < NNZ) bkt = ui_rows[i] >> 8;
        else         bkt = NSCAT_U + (iu_rows[i - NNZ] >> 8);
        atomicAdd(&h[bkt], 1);
    }
    __syncthreads();
    for (int t = threadIdx.x; t < NSCAT; t += 1024) {
        int c = h[t];
        bbase[t] = c ? atomicAdd(&gcursor[t], c) : 0;
        h[t] = 0;
    }
    __syncthreads();
    for (int j = threadIdx.x; j < CH_S; j += 1024) {
        int i = base + j;
        if (i >= NEDGES) break;
        int bkt, rl, src; float val;
        if (i < NNZ) {
            int r = ui_rows[i];
            bkt = r >> 8; rl = r & 255;
            src = NUSERS + ui_cols[i]; val = ui_vals[i];
        } else {
            int k = i - NNZ;
            int r = iu_rows[k];
            bkt = NSCAT_U + (r >> 8); rl = r & 255;
            src = iu_cols[k]; val = iu_vals[k];
        }
        int off = atomicAdd(&h[bkt], 1);
        binned[bbase[bkt] + off] = make_int2(src | (rl << 18), __float_as_int(val));
    }
}

// ---------------- coarse-bin sort: 2048 keys = 128 2-row-segments x 16 tiles ----------------
// One block (1024 thr) per coarse bin. Hierarchical shfl scan (4 barriers
// instead of ~22): per-wave inclusive scan over lanes, wave totals in LDS,
// per-thread carry = sum of preceding wave totals.
__global__ __launch_bounds__(1024) void csr_bin_sort_kernel(
    const int* __restrict__ gbase, const int* __restrict__ gcounts,
    const int2* __restrict__ binned, int2* __restrict__ binned2,
    int2* __restrict__ segptr)
{
    __shared__ int h[2048];
    __shared__ int off[2048];   // inclusive prefix
    __shared__ int cur[2048];
    __shared__ int wsum[16];
    int cb = blockIdx.x;
    bool isu = (cb < NSCAT_U);
    int s = gbase[cb];
    int n = gcounts[cb];
    int t = threadIdx.x;
    int lane = t & 63;
    int wid = t >> 6;           // 16 waves
    h[t] = 0; h[t + 1024] = 0;
    __syncthreads();
    for (int k = t; k < n; k += 1024) {
        unsigned w = (unsigned)binned[s + k].x;
        int rl = (int)(w >> 18);
        int src = (int)(w & 0x3FFFFu);
        atomicAdd(&h[(rl >> 1) * 16 + (src >> 14)], 1);
    }
    __syncthreads();
    // hierarchical scan: 2 keys/thread; wave shfl scan; cross-wave via wsum
    int e0 = h[2 * t], e1 = h[2 * t + 1];
    int ps = e0 + e1;
    int x = ps;
    for (int o = 1; o < 64; o <<= 1) {
        int u = __shfl_up(x, o, 64);
        if (lane >= o) x += u;
    }
    if (lane == 63) wsum[wid] = x;
    __syncthreads();
    int carry = 0;
#pragma unroll
    for (int w = 0; w < 16; ++w) carry += (w < wid) ? wsum[w] : 0;
    int excl = carry + x - ps;   // exclusive prefix for key 2t
    off[2 * t] = excl + e0;
    off[2 * t + 1] = excl + e0 + e1;
    cur[2 * t] = excl;
    cur[2 * t + 1] = excl + e0;
    __syncthreads();
    if (t < 128) {
        int start = s + ((t == 0) ? 0 : off[t * 16 - 1]);
        int end   = s + off[t * 16 + 15];
        int gseg = isu ? (cb * 128 + t)
                       : (SEG_IBASE + (cb - NSCAT_U) * 128 + t);
        segptr[gseg] = make_int2(start, end);
    }
    for (int k = t; k < n; k += 1024) {
        int2 m = binned[s + k];
        unsigned w = (unsigned)m.x;
        int rl = (int)(w >> 18);
        int src = (int)(w & 0x3FFFFu);
        int pos = atomicAdd(&cur[(rl >> 1) * 16 + (src >> 14)], 1);
        binned2[s + pos] = make_int2(src | ((rl & 1) << 18), m.y);
    }
}

// ---------------- segmented pull: uniform 2-row segments, reg-streamed cc ----------------
#define EDGE_ACC2(mx, my)                                                     \
    do {                                                                      \
        unsigned rr = ((unsigned)(mx) >> 18) & 1u;                            \
        float v = __int_as_float(my);                                         \
        uint2 xw = *(const uint2*)(xp + (size_t)((mx) & 0x3FFFF) * DIM);      \
        float xv0 = bf_lo(xw.x), xv1 = bf_hi(xw.x);                           \
        float xv2 = bf_lo(xw.y), xv3 = bf_hi(xw.y);                           \
        float p0 = rr ? 0.f : v;                                              \
        float p1 = rr ? v : 0.f;                                              \
        a0.x = fmaf(p0, xv0, a0.x); a0.y = fmaf(p0, xv1, a0.y);               \
        a0.z = fmaf(p0, xv2, a0.z); a0.w = fmaf(p0, xv3, a0.w);               \
        a1.x = fmaf(p1, xv0, a1.x); a1.y = fmaf(p1, xv1, a1.y);               \
        a1.z = fmaf(p1, xv2, a1.z); a1.w = fmaf(p1, xv3, a1.w);               \
    } while (0)

#define ROW_OUT(ar, r)                                                        \
    do {                                                                      \
        int row = row0 + (r);                                                 \
        if (row < TROWS) {                                                    \
            size_t obase = (size_t)row * DIM + l16 * 4;                       \
            uint2 eb = *(const uint2*)(xb0 + obase);                          \
            vfloat4 o;                                                        \
            o.x = fmaf(ALPHA, bf_lo(eb.x), (ar).x);                           \
            o.y = fmaf(ALPHA, bf_hi(eb.x), (ar).y);                           \
            o.z = fmaf(ALPHA, bf_lo(eb.y), (ar).z);                           \
            o.w = fmaf(ALPHA, bf_hi(eb.y), (ar).w);                           \
            __builtin_nontemporal_store(o, (vfloat4*)(outL + obase));         \
            if (WRITE_BF16) {                                                 \
                ushort4 bb;                                                   \
                bb.x = f2bf(o.x); bb.y = f2bf(o.y);                           \
                bb.z = f2bf(o.z); bb.w = f2bf(o.w);                           \
                *(ushort4*)(xb_next + obase) = bb;                            \
            }                                                                 \
        }                                                                     \
    } while (0)

template <int WRITE_BF16>
__global__ __launch_bounds__(256) void pull_seg_kernel(
    const int2* __restrict__ segptr,
    const int2* __restrict__ cc,
    const unsigned short* __restrict__ xb_prev,  // bf16 gather table (prev layer)
    const unsigned short* __restrict__ xb0,      // bf16 layer-0 table (alpha residual)
    float* __restrict__ outL,                    // f32 combined output layer
    unsigned short* __restrict__ xb_next)        // bf16 table for next layer
{
    int b = blockIdx.x;
    int wid = threadIdx.x >> 6;
    int lane = threadIdx.x & 63;
    int grp = lane >> 4;
    int l16 = lane & 15;
    int gb = lane & 48;       // group base lane
    int seg = wid * 4 + grp;

    const unsigned short* xp = xb_prev + l16 * 4;

    int segidx = (b < NBUCK_U) ? (b * 16 + seg)
                               : (SEG_IBASE + (b - NBUCK_U) * 16 + seg);
    int2 sp = segptr[segidx];
    int e = sp.x, end = sp.y;
    float4 a0 = make_float4(0.f, 0.f, 0.f, 0.f);
    float4 a1 = a0;

    while (e + 8 <= end) {
        int2 my = cc[e + (l16 & 7)];   // 8 edges of this group in registers
#pragma unroll
        for (int j = 0; j < 8; ++j) {
            int mx = __shfl(my.x, gb + j, 64);
            int mv = __shfl(my.y, gb + j, 64);
            EDGE_ACC2(mx, mv);
        }
        e += 8;
    }
    for (; e < end; ++e) {
        int2 m0 = cc[e];
        EDGE_ACC2(m0.x, m0.y);
    }

    int row0 = b * 32 + seg * 2;   // holds for users AND items (3125*32 == NUSERS)
    ROW_OUT(a0, 0);
    ROW_OUT(a1, 1);
}

// ---------------- fallback (round-1 atomic path) ----------------
__global__ __launch_bounds__(256) void init_out_kernel(const float4* __restrict__ ue,
                                                       const float4* __restrict__ ie,
                                                       float4* __restrict__ out) {
    const int nU4 = NUSERS * DIM / 4;
    const int nT4 = TROWS * DIM / 4;
    int i = blockIdx.x * 256 + threadIdx.x;
    if (i >= nT4) return;
    float4 v = (i < nU4) ? ue[i] : ie[i - nU4];
    out[i] = v;
    float4 a = make_float4(ALPHA * v.x, ALPHA * v.y, ALPHA * v.z, ALPHA * v.w);
    out[nT4 + i] = a;
    out[2 * nT4 + i] = a;
}

__global__ __launch_bounds__(256) void spmm_layer_kernel(
    const int* __restrict__ ui_rows, const int* __restrict__ ui_cols,
    const float* __restrict__ ui_vals,
    const int* __restrict__ iu_rows, const int* __restrict__ iu_cols,
    const float* __restrict__ iu_vals,
    const float* __restrict__ x_items, const float* __restrict__ x_users,
    float* __restrict__ y_users, float* __restrict__ y_items)
{
    unsigned tid = blockIdx.x * 256u + threadIdx.x;
    unsigned d = tid & 63u;
    unsigned e = tid >> 6;
    if (e < NNZ) {
        int r = ui_rows[e];
        int c = ui_cols[e];
        float v = ui_vals[e];
        atomicAdd(&y_users[r * DIM + d], v * x_items[c * DIM + d]);
    } else {
        e -= NNZ;
        if (e < NNZ) {
            int r = iu_rows[e];
            int c = iu_cols[e];
            float v = iu_vals[e];
            atomicAdd(&y_items[r * DIM + d], v * x_users[c * DIM + d]);
        }
    }
}

extern "C" void kernel_launch(void* const* d_in, const int* in_sizes, int n_in,
                              void* d_out, int out_size, void* d_ws, size_t ws_size,
                              hipStream_t stream) {
    const float* ue      = (const float*)d_in[0];
    const float* ie      = (const float*)d_in[1];
    const float* ui_vals = (const float*)d_in[2];
    const float* iu_vals = (const float*)d_in[3];
    const int*   ui_rows = (const int*)d_in[4];
    const int*   ui_cols = (const int*)d_in[5];
    const int*   iu_rows = (const int*)d_in[6];
    const int*   iu_cols = (const int*)d_in[7];
    float* out = (float*)d_out;

    float* L1 = out + (size_t)LSTRIDE;
    float* L2 = out + (size_t)2 * LSTRIDE;

    // ws layout: gcounts[1024] gbase[1024] gcursor[1024] | segptr int2[NSEG_PAD]
    //            | binned int2[NEDGES] | binned2 int2[NEDGES]
    //            | xb0 ushort[TROWS*64] | xb1 ushort[TROWS*64]
    const size_t NB_PAD = 1024;
    const size_t cnt_bytes    = NB_PAD * 3 * 4;              // 12288
    const size_t seg_bytes    = (size_t)NSEG_PAD * 8;        // 601088
    const size_t hdr_bytes    = cnt_bytes + seg_bytes;       // 613376, 8B-aligned
    const size_t binned_bytes = (size_t)NEDGES * 8;          // 25.6 MB
    const size_t xb_bytes     = (size_t)TROWS * DIM * 2;     // 19.2 MB
    const size_t need_bf16 = hdr_bytes + 2 * binned_bytes + 2 * xb_bytes;  // ~90.6 MB

    if (ws_size < need_bf16) {
        // fallback: atomic scatter path (round-1, known-good)
        const int nT4 = TROWS * DIM / 4;
        init_out_kernel<<<(nT4 + 255) / 256, 256, 0, stream>>>(
            (const float4*)ue, (const float4*)ie, (float4*)out);
        float* u1 = L1; float* i1 = L1 + (size_t)NUSERS * DIM;
        float* u2 = L2; float* i2 = L2 + (size_t)NUSERS * DIM;
        const unsigned nblocks = (2u * NNZ * 64u) / 256u;
        spmm_layer_kernel<<<nblocks, 256, 0, stream>>>(
            ui_rows, ui_cols, ui_vals, iu_rows, iu_cols, iu_vals, ie, ue, u1, i1);
        spmm_layer_kernel<<<nblocks, 256, 0, stream>>>(
            ui_rows, ui_cols, ui_vals, iu_rows, iu_cols, iu_vals, i1, u1, u2, i2);
        return;
    }

    int* gcounts = (int*)d_ws;
    int* gbase   = gcounts + NB_PAD;
    int* gcursor = gbase + NB_PAD;
    int2* segptr  = (int2*)((char*)d_ws + cnt_bytes);
    int2* binned  = (int2*)((char*)d_ws + hdr_bytes);
    int2* binned2 = (int2*)((char*)binned + binned_bytes);
    unsigned short* xb0 = (unsigned short*)((char*)binned2 + binned_bytes);
    unsigned short* xb1 = xb0 + (size_t)TROWS * DIM;

    hipMemsetAsync(gcounts, 0, NB_PAD * sizeof(int), stream);

    const int nT4 = TROWS * DIM / 4;
    init_copy_kernel<<<(nT4 + 255) / 256, 256, 0, stream>>>(
        (const float4*)ue, (const float4*)ie, (float4*)out, (ushort4*)xb0);

    bucket_hist_kernel<<<NCHUNK_H, 256, 0, stream>>>(
        (const int4*)ui_rows, (const int4*)iu_rows, gcounts);
    scan_buckets_kernel<<<1, 64, 0, stream>>>(gcounts, gbase, gcursor);
    bin_scatter_kernel<<<NCHUNK_S, 1024, 0, stream>>>(
        ui_rows, ui_cols, ui_vals, iu_rows, iu_cols, iu_vals, gcursor, binned);
    csr_bin_sort_kernel<<<NSCAT, 1024, 0, stream>>>(
        gbase, gcounts, binned, binned2, segptr);

    pull_seg_kernel<1><<<NBUCK, 256, 0, stream>>>(
        segptr, binned2, xb0, xb0, L1, xb1);
    pull_seg_kernel<0><<<NBUCK, 256, 0, stream>>>(
        segptr, binned2, xb1, xb0, L2, nullptr);
}